// Round 1
// baseline (608.838 us; speedup 1.0000x reference)
//
#include <hip/hip_runtime.h>
#include <hip/hip_bf16.h>

#define T_TOK 4096
#define D_DIM 1024
#define H_DIM 2048

typedef __attribute__((ext_vector_type(8))) short short8;
typedef __attribute__((ext_vector_type(4))) float floatx4;

__device__ __forceinline__ unsigned short f2bf(float f) {
  unsigned int u = __builtin_bit_cast(unsigned int, f);
  return (unsigned short)((u + 0x7fffu + ((u >> 16) & 1u)) >> 16);
}

__device__ __forceinline__ void glds16(const ushort* g, ushort* l) {
  __builtin_amdgcn_global_load_lds(
      (const __attribute__((address_space(1))) unsigned int*)g,
      (__attribute__((address_space(3))) unsigned int*)l, 16, 0, 0);
}

// ---------------- fp32 -> bf16 conversion ----------------
__global__ void cvt_kernel(const float4* __restrict__ src, ushort4* __restrict__ dst, int n4) {
  int i = blockIdx.x * 256 + threadIdx.x;
  if (i < n4) {
    float4 v = src[i];
    ushort4 o;
    o.x = f2bf(v.x); o.y = f2bf(v.y); o.z = f2bf(v.z); o.w = f2bf(v.w);
    dst[i] = o;
  }
}

// ---------------- router: logits, softmax, top-2, gather lists ----------------
__global__ void router_kernel(const float* __restrict__ x, const float* __restrict__ wr,
                              int* __restrict__ counts, int* __restrict__ list,
                              float* __restrict__ wlist) {
  int t = blockIdx.x;
  int l = threadIdx.x;  // 64 threads = 1 wave
  const float4* xr = (const float4*)(x + (size_t)t * D_DIM);
  float p[8];
#pragma unroll
  for (int e = 0; e < 8; ++e) p[e] = 0.f;
#pragma unroll
  for (int i = 0; i < 4; ++i) {
    float4 xv = xr[i * 64 + l];
#pragma unroll
    for (int e = 0; e < 8; ++e) {
      float4 wv = ((const float4*)(wr + e * D_DIM))[i * 64 + l];
      p[e] += xv.x * wv.x + xv.y * wv.y + xv.z * wv.z + xv.w * wv.w;
    }
  }
#pragma unroll
  for (int off = 32; off > 0; off >>= 1) {
#pragma unroll
    for (int e = 0; e < 8; ++e) p[e] += __shfl_xor(p[e], off, 64);
  }
  if (l == 0) {
    float mx = p[0];
#pragma unroll
    for (int e = 1; e < 8; ++e) mx = fmaxf(mx, p[e]);
    float pr[8];
#pragma unroll
    for (int e = 0; e < 8; ++e) pr[e] = __expf(p[e] - mx);
    // top-2; ties -> lower index (matches jax top_k)
    int i0 = 0;
#pragma unroll
    for (int e = 1; e < 8; ++e) if (pr[e] > pr[i0]) i0 = e;
    int i1 = (i0 == 0) ? 1 : 0;
#pragma unroll
    for (int e = 0; e < 8; ++e) if (e != i0 && pr[e] > pr[i1]) i1 = e;
    float w0 = pr[i0], w1 = pr[i1];
    float inv = 1.f / (w0 + w1);  // softmax denom cancels in renormalization
    w0 *= inv; w1 *= inv;
    int p0 = atomicAdd(&counts[i0], 1);
    list[i0 * T_TOK + p0] = t; wlist[i0 * T_TOK + p0] = w0;
    int p1 = atomicAdd(&counts[i1], 1);
    list[i1 * T_TOK + p1] = t; wlist[i1 * T_TOK + p1] = w1;
  }
}

// ---------------- exclusive prefix over 8 expert counts ----------------
__global__ void offsets_kernel(const int* __restrict__ counts, int* __restrict__ offs) {
  if (threadIdx.x == 0) {
    int acc = 0;
    for (int e = 0; e < 8; ++e) { offs[e] = acc; acc += counts[e]; }
    offs[8] = acc;  // == 8192 always
  }
}

// ---------------- GEMM1: fused gate+up, SwiGLU epilogue, h (bf16) ----------------
// grid: x = H col-tile (16), y = row-tile (32), z = expert (9; 8 == shared)
__global__ __launch_bounds__(256, 2)
void gemm1_kernel(const ushort* __restrict__ xb,
                  const ushort* __restrict__ Wgb, const ushort* __restrict__ Wub,
                  const ushort* __restrict__ sgb, const ushort* __restrict__ sub,
                  const int* __restrict__ list,
                  const int* __restrict__ counts, const int* __restrict__ offs,
                  ushort* __restrict__ h) {
  const int e = blockIdx.z;
  const int n_e = (e == 8) ? T_TOK : counts[e];
  const int r0 = blockIdx.y * 128;
  if (r0 >= n_e) return;
  const int c0 = blockIdx.x * 128;
  const ushort* Wg = (e == 8) ? sgb : (Wgb + (size_t)e * H_DIM * D_DIM);
  const ushort* Wu = (e == 8) ? sub : (Wub + (size_t)e * H_DIM * D_DIM);
  const int hrow0 = offs[e] + r0;

  __shared__ __align__(16) ushort As[128 * 32];
  __shared__ __align__(16) ushort Bgs[128 * 32];
  __shared__ __align__(16) ushort Bus[128 * 32];
  __shared__ int toks[128];

  const int tid = threadIdx.x;
  const int l = tid & 63;
  const int w = tid >> 6;

  if (tid < 128) {
    int rr = r0 + tid;
    toks[tid] = (e == 8) ? ((rr < T_TOK) ? rr : (T_TOK - 1))
                         : list[e * T_TOK + ((rr < n_e) ? rr : (n_e - 1))];
  }
  __syncthreads();

  // staging source pointers: inst i covers rows (w*2+i)*16 + l/4, k-chunk (l%4)*8
  const ushort* ag[2]; const ushort* bgp[2]; const ushort* bup[2];
#pragma unroll
  for (int i = 0; i < 2; ++i) {
    int row = (w * 2 + i) * 16 + (l >> 2);
    int kc = (l & 3) * 8;
    ag[i]  = xb + (size_t)toks[row] * D_DIM + kc;
    bgp[i] = Wg + (size_t)(c0 + row) * D_DIM + kc;
    bup[i] = Wu + (size_t)(c0 + row) * D_DIM + kc;
  }

  floatx4 accg[4][4], accu[4][4];
#pragma unroll
  for (int i = 0; i < 4; ++i)
#pragma unroll
    for (int j = 0; j < 4; ++j) {
      accg[i][j] = (floatx4)(0.f);
      accu[i][j] = (floatx4)(0.f);
    }

  const int mrow = (w & 1) * 64;
  const int ncol = (w >> 1) * 64;
  int aoff[4], boff[4];
#pragma unroll
  for (int i = 0; i < 4; ++i) {
    aoff[i] = (mrow + 16 * i + (l & 15)) * 32 + (l >> 4) * 8;
    boff[i] = (ncol + 16 * i + (l & 15)) * 32 + (l >> 4) * 8;
  }

  for (int k0 = 0; k0 < D_DIM; k0 += 32) {
    __syncthreads();
#pragma unroll
    for (int i = 0; i < 2; ++i) {
      glds16(ag[i] + k0,  As  + (w * 2 + i) * 512);
      glds16(bgp[i] + k0, Bgs + (w * 2 + i) * 512);
      glds16(bup[i] + k0, Bus + (w * 2 + i) * 512);
    }
    __syncthreads();
    short8 a[4], bg[4], bu[4];
#pragma unroll
    for (int i = 0; i < 4; ++i) a[i] = *(const short8*)(As + aoff[i]);
#pragma unroll
    for (int j = 0; j < 4; ++j) {
      bg[j] = *(const short8*)(Bgs + boff[j]);
      bu[j] = *(const short8*)(Bus + boff[j]);
    }
#pragma unroll
    for (int i = 0; i < 4; ++i)
#pragma unroll
      for (int j = 0; j < 4; ++j) {
        accg[i][j] = __builtin_amdgcn_mfma_f32_16x16x32_bf16(a[i], bg[j], accg[i][j], 0, 0, 0);
        accu[i][j] = __builtin_amdgcn_mfma_f32_16x16x32_bf16(a[i], bu[j], accu[i][j], 0, 0, 0);
      }
  }

  // epilogue: h = silu(g) * u, bf16
#pragma unroll
  for (int i = 0; i < 4; ++i) {
#pragma unroll
    for (int r = 0; r < 4; ++r) {
      int lrow = mrow + 16 * i + (l >> 4) * 4 + r;
      if (r0 + lrow < n_e) {
#pragma unroll
        for (int j = 0; j < 4; ++j) {
          float g = accg[i][j][r];
          float u = accu[i][j][r];
          float hv = (g / (1.f + __expf(-g))) * u;
          int col = c0 + ncol + 16 * j + (l & 15);
          h[(size_t)(hrow0 + lrow) * H_DIM + col] = f2bf(hv);
        }
      }
    }
  }
}

// ---------------- GEMM2: down-proj + weighted scatter-add ----------------
// grid: x = D col-tile (8), y = row-tile (32), z = expert (9)
__global__ __launch_bounds__(256, 2)
void gemm2_kernel(const ushort* __restrict__ h,
                  const ushort* __restrict__ Wdb, const ushort* __restrict__ sdb,
                  const int* __restrict__ list, const float* __restrict__ wlist,
                  const int* __restrict__ counts, const int* __restrict__ offs,
                  float* __restrict__ out) {
  const int e = blockIdx.z;
  const int n_e = (e == 8) ? T_TOK : counts[e];
  const int r0 = blockIdx.y * 128;
  if (r0 >= n_e) return;
  const int c0 = blockIdx.x * 128;
  const ushort* Wd = (e == 8) ? sdb : (Wdb + (size_t)e * D_DIM * H_DIM);
  const int hrow0 = offs[e] + r0;

  __shared__ __align__(16) ushort As[128 * 32];
  __shared__ __align__(16) ushort Bs[128 * 32];
  __shared__ int toks[128];
  __shared__ float wts[128];

  const int tid = threadIdx.x;
  const int l = tid & 63;
  const int w = tid >> 6;

  if (tid < 128) {
    int rr = r0 + tid;
    if (e == 8) {
      toks[tid] = (rr < T_TOK) ? rr : (T_TOK - 1);
      wts[tid] = 1.0f;
    } else {
      int idx = (rr < n_e) ? rr : (n_e - 1);
      toks[tid] = list[e * T_TOK + idx];
      wts[tid] = (rr < n_e) ? wlist[e * T_TOK + idx] : 0.f;
    }
  }

  const ushort* ag[2]; const ushort* bp[2];
#pragma unroll
  for (int i = 0; i < 2; ++i) {
    int row = (w * 2 + i) * 16 + (l >> 2);
    int kc = (l & 3) * 8;
    ag[i] = h  + (size_t)(hrow0 + row) * H_DIM + kc;
    bp[i] = Wd + (size_t)(c0 + row) * H_DIM + kc;
  }

  floatx4 acc[4][4];
#pragma unroll
  for (int i = 0; i < 4; ++i)
#pragma unroll
    for (int j = 0; j < 4; ++j) acc[i][j] = (floatx4)(0.f);

  const int mrow = (w & 1) * 64;
  const int ncol = (w >> 1) * 64;
  int aoff[4], boff[4];
#pragma unroll
  for (int i = 0; i < 4; ++i) {
    aoff[i] = (mrow + 16 * i + (l & 15)) * 32 + (l >> 4) * 8;
    boff[i] = (ncol + 16 * i + (l & 15)) * 32 + (l >> 4) * 8;
  }

  for (int k0 = 0; k0 < H_DIM; k0 += 32) {
    __syncthreads();
#pragma unroll
    for (int i = 0; i < 2; ++i) {
      glds16(ag[i] + k0, As + (w * 2 + i) * 512);
      glds16(bp[i] + k0, Bs + (w * 2 + i) * 512);
    }
    __syncthreads();
    short8 a[4], b[4];
#pragma unroll
    for (int i = 0; i < 4; ++i) a[i] = *(const short8*)(As + aoff[i]);
#pragma unroll
    for (int j = 0; j < 4; ++j) b[j] = *(const short8*)(Bs + boff[j]);
#pragma unroll
    for (int i = 0; i < 4; ++i)
#pragma unroll
      for (int j = 0; j < 4; ++j)
        acc[i][j] = __builtin_amdgcn_mfma_f32_16x16x32_bf16(a[i], b[j], acc[i][j], 0, 0, 0);
  }

  // epilogue: weighted atomic scatter-add
#pragma unroll
  for (int i = 0; i < 4; ++i) {
#pragma unroll
    for (int r = 0; r < 4; ++r) {
      int lrow = mrow + 16 * i + (l >> 4) * 4 + r;
      if (r0 + lrow < n_e) {
        int tok = toks[lrow];
        float wt = wts[lrow];
#pragma unroll
        for (int j = 0; j < 4; ++j) {
          int col = c0 + ncol + 16 * j + (l & 15);
          atomicAdd(&out[(size_t)tok * D_DIM + col], wt * acc[i][j][r]);
        }
      }
    }
  }
}

// ---------------- workspace layout ----------------
#define OFF_XB   0ull
#define OFF_WGB  (OFF_XB + 8388608ull)
#define OFF_WUB  (OFF_WGB + 33554432ull)
#define OFF_WDB  (OFF_WUB + 33554432ull)
#define OFF_SGB  (OFF_WDB + 33554432ull)
#define OFF_SUB  (OFF_SGB + 4194304ull)
#define OFF_SDB  (OFF_SUB + 4194304ull)
#define OFF_H    (OFF_SDB + 4194304ull)
#define OFF_CNT  (OFF_H + 50331648ull)
#define OFF_OFFS (OFF_CNT + 64ull)
#define OFF_LIST (OFF_OFFS + 64ull)
#define OFF_WLST (OFF_LIST + 131072ull)

extern "C" void kernel_launch(void* const* d_in, const int* in_sizes, int n_in,
                              void* d_out, int out_size, void* d_ws, size_t ws_size,
                              hipStream_t stream) {
  const float* x  = (const float*)d_in[0];
  const float* wr = (const float*)d_in[1];
  const float* Wg = (const float*)d_in[2];
  const float* Wu = (const float*)d_in[3];
  const float* Wd = (const float*)d_in[4];
  const float* sg = (const float*)d_in[5];
  const float* su = (const float*)d_in[6];
  const float* sd = (const float*)d_in[7];
  float* out = (float*)d_out;
  char* ws = (char*)d_ws;

  ushort* xb  = (ushort*)(ws + OFF_XB);
  ushort* Wgb = (ushort*)(ws + OFF_WGB);
  ushort* Wub = (ushort*)(ws + OFF_WUB);
  ushort* Wdb = (ushort*)(ws + OFF_WDB);
  ushort* sgb = (ushort*)(ws + OFF_SGB);
  ushort* sub = (ushort*)(ws + OFF_SUB);
  ushort* sdb = (ushort*)(ws + OFF_SDB);
  ushort* hbuf = (ushort*)(ws + OFF_H);
  int* counts = (int*)(ws + OFF_CNT);
  int* offs   = (int*)(ws + OFF_OFFS);
  int* list   = (int*)(ws + OFF_LIST);
  float* wlist = (float*)(ws + OFF_WLST);

  hipMemsetAsync(d_out, 0, (size_t)out_size * sizeof(float), stream);
  hipMemsetAsync(counts, 0, 64, stream);

  cvt_kernel<<<4096, 256, 0, stream>>>((const float4*)x, (ushort4*)xb, 1048576);
  cvt_kernel<<<16384, 256, 0, stream>>>((const float4*)Wg, (ushort4*)Wgb, 4194304);
  cvt_kernel<<<16384, 256, 0, stream>>>((const float4*)Wu, (ushort4*)Wub, 4194304);
  cvt_kernel<<<16384, 256, 0, stream>>>((const float4*)Wd, (ushort4*)Wdb, 4194304);
  cvt_kernel<<<2048, 256, 0, stream>>>((const float4*)sg, (ushort4*)sgb, 524288);
  cvt_kernel<<<2048, 256, 0, stream>>>((const float4*)su, (ushort4*)sub, 524288);
  cvt_kernel<<<2048, 256, 0, stream>>>((const float4*)sd, (ushort4*)sdb, 524288);

  router_kernel<<<4096, 64, 0, stream>>>(x, wr, counts, list, wlist);
  offsets_kernel<<<1, 64, 0, stream>>>(counts, offs);

  gemm1_kernel<<<dim3(16, 32, 9), 256, 0, stream>>>(xb, Wgb, Wub, sgb, sub,
                                                    list, counts, offs, hbuf);
  gemm2_kernel<<<dim3(8, 32, 9), 256, 0, stream>>>(hbuf, Wdb, sdb,
                                                   list, wlist, counts, offs, out);
}

// Round 2
// 562.453 us; speedup vs baseline: 1.0825x; 1.0825x over previous
//
#include <hip/hip_runtime.h>
#include <hip/hip_bf16.h>

#define T_TOK 4096
#define D_DIM 1024
#define H_DIM 2048

typedef __attribute__((ext_vector_type(8))) short short8;
typedef __attribute__((ext_vector_type(4))) float floatx4;

__device__ __forceinline__ unsigned short f2bf(float f) {
  unsigned int u = __builtin_bit_cast(unsigned int, f);
  return (unsigned short)((u + 0x7fffu + ((u >> 16) & 1u)) >> 16);
}

__device__ __forceinline__ void glds16(const ushort* g, ushort* l) {
  __builtin_amdgcn_global_load_lds(
      (const __attribute__((address_space(1))) unsigned int*)g,
      (__attribute__((address_space(3))) unsigned int*)l, 16, 0, 0);
}

// ---------------- fp32 -> bf16 conversion, 3 tensors per launch ----------------
__global__ void cvt_w_kernel(const float4* __restrict__ w0, ushort4* __restrict__ o0,
                             const float4* __restrict__ w1, ushort4* __restrict__ o1,
                             const float4* __restrict__ w2, ushort4* __restrict__ o2,
                             int n4) {
  const float4* s; ushort4* d;
  if (blockIdx.y == 0)      { s = w0; d = o0; }
  else if (blockIdx.y == 1) { s = w1; d = o1; }
  else                      { s = w2; d = o2; }
  int i = blockIdx.x * 256 + threadIdx.x;
  if (i < n4) {
    float4 v = s[i];
    ushort4 o;
    o.x = f2bf(v.x); o.y = f2bf(v.y); o.z = f2bf(v.z); o.w = f2bf(v.w);
    d[i] = o;
  }
}

// ---------------- router: logits, softmax, top-2, gather lists; fused x->bf16 ----------------
__global__ void router_kernel(const float* __restrict__ x, const float* __restrict__ wr,
                              ushort* __restrict__ xb,
                              int* __restrict__ counts, int* __restrict__ list,
                              float* __restrict__ wlist) {
  int t = blockIdx.x;
  int l = threadIdx.x;  // 64 threads = 1 wave
  const float4* xr = (const float4*)(x + (size_t)t * D_DIM);
  ushort4* xo = (ushort4*)(xb + (size_t)t * D_DIM);
  float p[8];
#pragma unroll
  for (int e = 0; e < 8; ++e) p[e] = 0.f;
#pragma unroll
  for (int i = 0; i < 4; ++i) {
    float4 xv = xr[i * 64 + l];
    ushort4 o;
    o.x = f2bf(xv.x); o.y = f2bf(xv.y); o.z = f2bf(xv.z); o.w = f2bf(xv.w);
    xo[i * 64 + l] = o;
#pragma unroll
    for (int e = 0; e < 8; ++e) {
      float4 wv = ((const float4*)(wr + e * D_DIM))[i * 64 + l];
      p[e] += xv.x * wv.x + xv.y * wv.y + xv.z * wv.z + xv.w * wv.w;
    }
  }
#pragma unroll
  for (int off = 32; off > 0; off >>= 1) {
#pragma unroll
    for (int e = 0; e < 8; ++e) p[e] += __shfl_xor(p[e], off, 64);
  }
  if (l == 0) {
    float mx = p[0];
#pragma unroll
    for (int e = 1; e < 8; ++e) mx = fmaxf(mx, p[e]);
    float pr[8];
#pragma unroll
    for (int e = 0; e < 8; ++e) pr[e] = __expf(p[e] - mx);
    int i0 = 0;
#pragma unroll
    for (int e = 1; e < 8; ++e) if (pr[e] > pr[i0]) i0 = e;
    int i1 = (i0 == 0) ? 1 : 0;
#pragma unroll
    for (int e = 0; e < 8; ++e) if (e != i0 && pr[e] > pr[i1]) i1 = e;
    float w0 = pr[i0], w1 = pr[i1];
    float inv = 1.f / (w0 + w1);
    w0 *= inv; w1 *= inv;
    int p0 = atomicAdd(&counts[i0], 1);
    list[i0 * T_TOK + p0] = t; wlist[i0 * T_TOK + p0] = w0;
    int p1 = atomicAdd(&counts[i1], 1);
    list[i1 * T_TOK + p1] = t; wlist[i1 * T_TOK + p1] = w1;
  }
}

__global__ void offsets_kernel(const int* __restrict__ counts, int* __restrict__ offs) {
  if (threadIdx.x == 0) {
    int acc = 0;
    for (int e = 0; e < 8; ++e) { offs[e] = acc; acc += counts[e]; }
    offs[8] = acc;
  }
}

// ---------------- GEMM1: fused gate+up, SwiGLU epilogue -> h (bf16) ----------------
// BK=64, XOR bank swizzle: LDS row r physical chunk p holds global chunk p^(r&7).
// grid: x = H col-tile (16), y = row-tile (32), z = expert (9; 8 == shared)
__global__ __launch_bounds__(256, 2)
void gemm1_kernel(const ushort* __restrict__ xb,
                  const ushort* __restrict__ Wgb, const ushort* __restrict__ Wub,
                  const ushort* __restrict__ sgb, const ushort* __restrict__ sub,
                  const int* __restrict__ list,
                  const int* __restrict__ counts, const int* __restrict__ offs,
                  ushort* __restrict__ h) {
  const int e = blockIdx.z;
  const int n_e = (e == 8) ? T_TOK : counts[e];
  const int r0 = blockIdx.y * 128;
  if (r0 >= n_e) return;
  const int c0 = blockIdx.x * 128;
  const ushort* Wg = (e == 8) ? sgb : (Wgb + (size_t)e * H_DIM * D_DIM);
  const ushort* Wu = (e == 8) ? sub : (Wub + (size_t)e * H_DIM * D_DIM);
  const int hrow0 = offs[e] + r0;

  __shared__ __align__(16) ushort As[128 * 64];
  __shared__ __align__(16) ushort Bgs[128 * 64];
  __shared__ __align__(16) ushort Bus[128 * 64];
  __shared__ int toks[128];

  const int tid = threadIdx.x;
  const int l = tid & 63;
  const int w = tid >> 6;

  if (tid < 128) {
    int rr = r0 + tid;
    toks[tid] = (e == 8) ? ((rr < T_TOK) ? rr : (T_TOK - 1))
                         : list[e * T_TOK + ((rr < n_e) ? rr : (n_e - 1))];
  }
  __syncthreads();

  // staging: inst i covers rows (w*4+i)*8 + l/8; lane writes LDS base + l*16B
  // global k-chunk c = (l&7) ^ (l>>3)  (XOR swizzle; row&7 == l>>3 here)
  const int lrow8 = l >> 3;
  const int csw = (((l & 7) ^ lrow8) << 3);  // element offset of swizzled chunk
  const ushort* ap[4];
#pragma unroll
  for (int i = 0; i < 4; ++i) {
    int ri = (w * 4 + i) * 8 + lrow8;
    ap[i] = xb + (size_t)toks[ri] * D_DIM + csw;
  }
  const ushort* bgp = Wg + (size_t)(c0 + w * 32 + lrow8) * D_DIM + csw;
  const ushort* bup = Wu + (size_t)(c0 + w * 32 + lrow8) * D_DIM + csw;

  floatx4 accg[4][4], accu[4][4];
#pragma unroll
  for (int i = 0; i < 4; ++i)
#pragma unroll
    for (int j = 0; j < 4; ++j) {
      accg[i][j] = (floatx4)(0.f);
      accu[i][j] = (floatx4)(0.f);
    }

  const int mrow = (w & 1) * 64;
  const int ncol = (w >> 1) * 64;
  int rba[4], rbb[4];
#pragma unroll
  for (int i = 0; i < 4; ++i) {
    rba[i] = (mrow + 16 * i + (l & 15)) * 64;
    rbb[i] = (ncol + 16 * i + (l & 15)) * 64;
  }

  for (int k0 = 0; k0 < D_DIM; k0 += 64) {
    __syncthreads();
#pragma unroll
    for (int i = 0; i < 4; ++i) {
      glds16(ap[i] + k0,                As  + (w * 4 + i) * 512);
      glds16(bgp + k0 + i * 8 * D_DIM,  Bgs + (w * 4 + i) * 512);
      glds16(bup + k0 + i * 8 * D_DIM,  Bus + (w * 4 + i) * 512);
    }
    __syncthreads();
#pragma unroll
    for (int s = 0; s < 2; ++s) {
      const int pq = ((((s << 2) | (l >> 4)) ^ (l & 7)) << 3);
      short8 a[4], bg[4], bu[4];
#pragma unroll
      for (int i = 0; i < 4; ++i) a[i] = *(const short8*)(As + rba[i] + pq);
#pragma unroll
      for (int j = 0; j < 4; ++j) {
        bg[j] = *(const short8*)(Bgs + rbb[j] + pq);
        bu[j] = *(const short8*)(Bus + rbb[j] + pq);
      }
#pragma unroll
      for (int i = 0; i < 4; ++i)
#pragma unroll
        for (int j = 0; j < 4; ++j) {
          accg[i][j] = __builtin_amdgcn_mfma_f32_16x16x32_bf16(a[i], bg[j], accg[i][j], 0, 0, 0);
          accu[i][j] = __builtin_amdgcn_mfma_f32_16x16x32_bf16(a[i], bu[j], accu[i][j], 0, 0, 0);
        }
    }
  }

#pragma unroll
  for (int i = 0; i < 4; ++i) {
#pragma unroll
    for (int r = 0; r < 4; ++r) {
      int lrow = mrow + 16 * i + (l >> 4) * 4 + r;
      if (r0 + lrow < n_e) {
#pragma unroll
        for (int j = 0; j < 4; ++j) {
          float g = accg[i][j][r];
          float u = accu[i][j][r];
          float hv = (g / (1.f + __expf(-g))) * u;
          int col = c0 + ncol + 16 * j + (l & 15);
          h[(size_t)(hrow0 + lrow) * H_DIM + col] = f2bf(hv);
        }
      }
    }
  }
}

// ---------------- GEMM2: down-proj + weighted scatter-add ----------------
// grid: x = D col-tile (8), y = row-tile (32), z = expert (9)
__global__ __launch_bounds__(256, 3)
void gemm2_kernel(const ushort* __restrict__ h,
                  const ushort* __restrict__ Wdb, const ushort* __restrict__ sdb,
                  const int* __restrict__ list, const float* __restrict__ wlist,
                  const int* __restrict__ counts, const int* __restrict__ offs,
                  float* __restrict__ out) {
  const int e = blockIdx.z;
  const int n_e = (e == 8) ? T_TOK : counts[e];
  const int r0 = blockIdx.y * 128;
  if (r0 >= n_e) return;
  const int c0 = blockIdx.x * 128;
  const ushort* Wd = (e == 8) ? sdb : (Wdb + (size_t)e * D_DIM * H_DIM);
  const int hrow0 = offs[e] + r0;

  __shared__ __align__(16) ushort As[128 * 64];
  __shared__ __align__(16) ushort Bs[128 * 64];
  __shared__ int toks[128];
  __shared__ float wts[128];

  const int tid = threadIdx.x;
  const int l = tid & 63;
  const int w = tid >> 6;

  if (tid < 128) {
    int rr = r0 + tid;
    if (e == 8) {
      toks[tid] = (rr < T_TOK) ? rr : (T_TOK - 1);
      wts[tid] = 1.0f;
    } else {
      int idx = (rr < n_e) ? rr : (n_e - 1);
      toks[tid] = list[e * T_TOK + idx];
      wts[tid] = (rr < n_e) ? wlist[e * T_TOK + idx] : 0.f;
    }
  }

  const int lrow8 = l >> 3;
  const int csw = (((l & 7) ^ lrow8) << 3);
  const ushort* apb = h  + (size_t)(hrow0 + w * 32 + lrow8) * H_DIM + csw;
  const ushort* bpb = Wd + (size_t)(c0 + w * 32 + lrow8) * H_DIM + csw;

  floatx4 acc[4][4];
#pragma unroll
  for (int i = 0; i < 4; ++i)
#pragma unroll
    for (int j = 0; j < 4; ++j) acc[i][j] = (floatx4)(0.f);

  const int mrow = (w & 1) * 64;
  const int ncol = (w >> 1) * 64;
  int rba[4], rbb[4];
#pragma unroll
  for (int i = 0; i < 4; ++i) {
    rba[i] = (mrow + 16 * i + (l & 15)) * 64;
    rbb[i] = (ncol + 16 * i + (l & 15)) * 64;
  }

  for (int k0 = 0; k0 < H_DIM; k0 += 64) {
    __syncthreads();
#pragma unroll
    for (int i = 0; i < 4; ++i) {
      glds16(apb + k0 + i * 8 * H_DIM, As + (w * 4 + i) * 512);
      glds16(bpb + k0 + i * 8 * H_DIM, Bs + (w * 4 + i) * 512);
    }
    __syncthreads();
#pragma unroll
    for (int s = 0; s < 2; ++s) {
      const int pq = ((((s << 2) | (l >> 4)) ^ (l & 7)) << 3);
      short8 a[4], b[4];
#pragma unroll
      for (int i = 0; i < 4; ++i) a[i] = *(const short8*)(As + rba[i] + pq);
#pragma unroll
      for (int j = 0; j < 4; ++j) b[j] = *(const short8*)(Bs + rbb[j] + pq);
#pragma unroll
      for (int i = 0; i < 4; ++i)
#pragma unroll
        for (int j = 0; j < 4; ++j)
          acc[i][j] = __builtin_amdgcn_mfma_f32_16x16x32_bf16(a[i], b[j], acc[i][j], 0, 0, 0);
    }
  }

#pragma unroll
  for (int i = 0; i < 4; ++i) {
#pragma unroll
    for (int r = 0; r < 4; ++r) {
      int lrow = mrow + 16 * i + (l >> 4) * 4 + r;
      if (r0 + lrow < n_e) {
        int tok = toks[lrow];
        float wt = wts[lrow];
#pragma unroll
        for (int j = 0; j < 4; ++j) {
          int col = c0 + ncol + 16 * j + (l & 15);
          atomicAdd(&out[(size_t)tok * D_DIM + col], wt * acc[i][j][r]);
        }
      }
    }
  }
}

// ---------------- workspace layout ----------------
#define OFF_XB   0ull
#define OFF_WGB  (OFF_XB + 8388608ull)
#define OFF_WUB  (OFF_WGB + 33554432ull)
#define OFF_WDB  (OFF_WUB + 33554432ull)
#define OFF_SGB  (OFF_WDB + 33554432ull)
#define OFF_SUB  (OFF_SGB + 4194304ull)
#define OFF_SDB  (OFF_SUB + 4194304ull)
#define OFF_H    (OFF_SDB + 4194304ull)
#define OFF_CNT  (OFF_H + 50331648ull)
#define OFF_OFFS (OFF_CNT + 64ull)
#define OFF_LIST (OFF_OFFS + 64ull)
#define OFF_WLST (OFF_LIST + 131072ull)

extern "C" void kernel_launch(void* const* d_in, const int* in_sizes, int n_in,
                              void* d_out, int out_size, void* d_ws, size_t ws_size,
                              hipStream_t stream) {
  const float* x  = (const float*)d_in[0];
  const float* wr = (const float*)d_in[1];
  const float* Wg = (const float*)d_in[2];
  const float* Wu = (const float*)d_in[3];
  const float* Wd = (const float*)d_in[4];
  const float* sg = (const float*)d_in[5];
  const float* su = (const float*)d_in[6];
  const float* sd = (const float*)d_in[7];
  float* out = (float*)d_out;
  char* ws = (char*)d_ws;

  ushort* xb  = (ushort*)(ws + OFF_XB);
  ushort* Wgb = (ushort*)(ws + OFF_WGB);
  ushort* Wub = (ushort*)(ws + OFF_WUB);
  ushort* Wdb = (ushort*)(ws + OFF_WDB);
  ushort* sgb = (ushort*)(ws + OFF_SGB);
  ushort* sub = (ushort*)(ws + OFF_SUB);
  ushort* sdb = (ushort*)(ws + OFF_SDB);
  ushort* hbuf = (ushort*)(ws + OFF_H);
  int* counts = (int*)(ws + OFF_CNT);
  int* offs   = (int*)(ws + OFF_OFFS);
  int* list   = (int*)(ws + OFF_LIST);
  float* wlist = (float*)(ws + OFF_WLST);

  hipMemsetAsync(d_out, 0, (size_t)out_size * sizeof(float), stream);
  hipMemsetAsync(counts, 0, 64, stream);

  cvt_w_kernel<<<dim3(16384, 3), 256, 0, stream>>>((const float4*)Wg, (ushort4*)Wgb,
                                                   (const float4*)Wu, (ushort4*)Wub,
                                                   (const float4*)Wd, (ushort4*)Wdb, 4194304);
  cvt_w_kernel<<<dim3(2048, 3), 256, 0, stream>>>((const float4*)sg, (ushort4*)sgb,
                                                  (const float4*)su, (ushort4*)sub,
                                                  (const float4*)sd, (ushort4*)sdb, 524288);

  router_kernel<<<4096, 64, 0, stream>>>(x, wr, xb, counts, list, wlist);
  offsets_kernel<<<1, 64, 0, stream>>>(counts, offs);

  gemm1_kernel<<<dim3(16, 32, 9), 256, 0, stream>>>(xb, Wgb, Wub, sgb, sub,
                                                    list, counts, offs, hbuf);
  gemm2_kernel<<<dim3(8, 32, 9), 256, 0, stream>>>(hbuf, Wdb, sdb,
                                                   list, wlist, counts, offs, out);
}

// Round 3
// 481.207 us; speedup vs baseline: 1.2652x; 1.1688x over previous
//
#include <hip/hip_runtime.h>
#include <hip/hip_bf16.h>

#define T_TOK 4096
#define D_DIM 1024
#define H_DIM 2048

typedef __attribute__((ext_vector_type(8))) short short8;
typedef __attribute__((ext_vector_type(4))) float floatx4;

__device__ __forceinline__ unsigned short f2bf(float f) {
  unsigned int u = __builtin_bit_cast(unsigned int, f);
  return (unsigned short)((u + 0x7fffu + ((u >> 16) & 1u)) >> 16);
}

__device__ __forceinline__ void glds16(const ushort* g, ushort* l) {
  __builtin_amdgcn_global_load_lds(
      (const __attribute__((address_space(1))) unsigned int*)g,
      (__attribute__((address_space(3))) unsigned int*)l, 16, 0, 0);
}

// ---------------- fp32 -> bf16 conversion, all 6 weight tensors, flat grid ----------------
// blocks 0..49151: Wg/Wu/Wd (16384 each); 49152..55295: sg/su/sd (2048 each)
__global__ void cvt_all_kernel(const float4* __restrict__ Wg, ushort4* __restrict__ Wgb,
                               const float4* __restrict__ Wu, ushort4* __restrict__ Wub,
                               const float4* __restrict__ Wd, ushort4* __restrict__ Wdb,
                               const float4* __restrict__ sg, ushort4* __restrict__ sgb,
                               const float4* __restrict__ su, ushort4* __restrict__ sub,
                               const float4* __restrict__ sd, ushort4* __restrict__ sdb) {
  int id = blockIdx.x;
  const float4* s; ushort4* d; int i;
  if (id < 49152) {
    int seg = id >> 14;           // /16384
    int blk = id & 16383;
    s = (seg == 0) ? Wg : (seg == 1) ? Wu : Wd;
    d = (seg == 0) ? Wgb : (seg == 1) ? Wub : Wdb;
    i = blk * 256 + threadIdx.x;
  } else {
    int id2 = id - 49152;
    int seg = id2 >> 11;          // /2048
    int blk = id2 & 2047;
    s = (seg == 0) ? sg : (seg == 1) ? su : sd;
    d = (seg == 0) ? sgb : (seg == 1) ? sub : sdb;
    i = blk * 256 + threadIdx.x;
  }
  float4 v = s[i];
  ushort4 o;
  o.x = f2bf(v.x); o.y = f2bf(v.y); o.z = f2bf(v.z); o.w = f2bf(v.w);
  d[i] = o;
}

// ---------------- router: logits, softmax, top-2 per token; fused x->bf16; NO atomics ----------------
__global__ void router_kernel(const float* __restrict__ x, const float* __restrict__ wr,
                              ushort* __restrict__ xb,
                              int* __restrict__ topi, float2* __restrict__ topw) {
  const int w = threadIdx.x >> 6;
  const int l = threadIdx.x & 63;
  const int t = blockIdx.x * 4 + w;  // one token per wave
  const float4* xr = (const float4*)(x + (size_t)t * D_DIM);
  ushort4* xo = (ushort4*)(xb + (size_t)t * D_DIM);
  float p[8];
#pragma unroll
  for (int e = 0; e < 8; ++e) p[e] = 0.f;
#pragma unroll
  for (int i = 0; i < 4; ++i) {
    float4 xv = xr[i * 64 + l];
    ushort4 o;
    o.x = f2bf(xv.x); o.y = f2bf(xv.y); o.z = f2bf(xv.z); o.w = f2bf(xv.w);
    xo[i * 64 + l] = o;
#pragma unroll
    for (int e = 0; e < 8; ++e) {
      float4 wv = ((const float4*)(wr + e * D_DIM))[i * 64 + l];
      p[e] += xv.x * wv.x + xv.y * wv.y + xv.z * wv.z + xv.w * wv.w;
    }
  }
#pragma unroll
  for (int off = 32; off > 0; off >>= 1) {
#pragma unroll
    for (int e = 0; e < 8; ++e) p[e] += __shfl_xor(p[e], off, 64);
  }
  if (l == 0) {
    float mx = p[0];
#pragma unroll
    for (int e = 1; e < 8; ++e) mx = fmaxf(mx, p[e]);
    float pr[8];
#pragma unroll
    for (int e = 0; e < 8; ++e) pr[e] = __expf(p[e] - mx);
    int i0 = 0;
#pragma unroll
    for (int e = 1; e < 8; ++e) if (pr[e] > pr[i0]) i0 = e;
    int i1 = (i0 == 0) ? 1 : 0;
#pragma unroll
    for (int e = 0; e < 8; ++e) if (e != i0 && pr[e] > pr[i1]) i1 = e;
    float w0 = pr[i0], w1 = pr[i1];
    float inv = 1.f / (w0 + w1);
    topi[t] = i0 | (i1 << 8);
    topw[t] = make_float2(w0 * inv, w1 * inv);
  }
}

// ---------------- deterministic list build: 8 blocks, ballot prefix-sum compaction ----------------
__global__ void build_lists_kernel(const int* __restrict__ topi, const float2* __restrict__ topw,
                                   int* __restrict__ counts, int* __restrict__ list,
                                   float* __restrict__ wlist) {
  const int e = blockIdx.x;
  const int tid = threadIdx.x;
  const int l = tid & 63;
  const int w = tid >> 6;
  __shared__ int wtot[4];
  int base = 0;
  for (int c = 0; c < T_TOK; c += 256) {
    int t = c + tid;
    int ti = topi[t];
    int e0 = ti & 255, e1 = ti >> 8;
    bool flag = (e0 == e) || (e1 == e);
    float2 tw = topw[t];
    float wv = (e0 == e) ? tw.x : tw.y;
    unsigned long long m = __ballot(flag);
    int lanepos = __popcll(m & ((1ull << l) - 1ull));
    if (l == 0) wtot[w] = __popcll(m);
    __syncthreads();
    int waveoff = 0;
#pragma unroll
    for (int i = 0; i < 4; ++i) waveoff += (i < w) ? wtot[i] : 0;
    int tot = wtot[0] + wtot[1] + wtot[2] + wtot[3];
    if (flag) {
      int p = base + waveoff + lanepos;
      list[e * T_TOK + p] = t;
      wlist[e * T_TOK + p] = wv;
    }
    base += tot;
    __syncthreads();
  }
  if (tid == 0) counts[e] = base;
}

__global__ void offsets_kernel(const int* __restrict__ counts, int* __restrict__ offs) {
  if (threadIdx.x == 0) {
    int acc = 0;
    for (int e = 0; e < 8; ++e) { offs[e] = acc; acc += counts[e]; }
    offs[8] = acc;
  }
}

// ---------------- GEMM1: fused gate+up, SwiGLU epilogue -> h (bf16) ----------------
// BK=64, XOR bank swizzle: LDS row r physical chunk p holds global chunk p^(r&7).
// grid: x = H col-tile (16), y = row-tile (32), z = expert (9; 8 == shared)
__global__ __launch_bounds__(256, 2)
void gemm1_kernel(const ushort* __restrict__ xb,
                  const ushort* __restrict__ Wgb, const ushort* __restrict__ Wub,
                  const ushort* __restrict__ sgb, const ushort* __restrict__ sub,
                  const int* __restrict__ list,
                  const int* __restrict__ counts, const int* __restrict__ offs,
                  ushort* __restrict__ h) {
  const int e = blockIdx.z;
  const int n_e = (e == 8) ? T_TOK : counts[e];
  const int r0 = blockIdx.y * 128;
  if (r0 >= n_e) return;
  const int c0 = blockIdx.x * 128;
  const ushort* Wg = (e == 8) ? sgb : (Wgb + (size_t)e * H_DIM * D_DIM);
  const ushort* Wu = (e == 8) ? sub : (Wub + (size_t)e * H_DIM * D_DIM);
  const int hrow0 = offs[e] + r0;

  __shared__ __align__(16) ushort As[128 * 64];
  __shared__ __align__(16) ushort Bgs[128 * 64];
  __shared__ __align__(16) ushort Bus[128 * 64];
  __shared__ int toks[128];

  const int tid = threadIdx.x;
  const int l = tid & 63;
  const int w = tid >> 6;

  if (tid < 128) {
    int rr = r0 + tid;
    toks[tid] = (e == 8) ? ((rr < T_TOK) ? rr : (T_TOK - 1))
                         : list[e * T_TOK + ((rr < n_e) ? rr : (n_e - 1))];
  }
  __syncthreads();

  const int lrow8 = l >> 3;
  const int csw = (((l & 7) ^ lrow8) << 3);  // XOR-swizzled k-chunk (element offset)
  const ushort* ap[4];
#pragma unroll
  for (int i = 0; i < 4; ++i) {
    int ri = (w * 4 + i) * 8 + lrow8;
    ap[i] = xb + (size_t)toks[ri] * D_DIM + csw;
  }
  const ushort* bgp = Wg + (size_t)(c0 + w * 32 + lrow8) * D_DIM + csw;
  const ushort* bup = Wu + (size_t)(c0 + w * 32 + lrow8) * D_DIM + csw;

  floatx4 accg[4][4], accu[4][4];
#pragma unroll
  for (int i = 0; i < 4; ++i)
#pragma unroll
    for (int j = 0; j < 4; ++j) {
      accg[i][j] = (floatx4)(0.f);
      accu[i][j] = (floatx4)(0.f);
    }

  const int mrow = (w & 1) * 64;
  const int ncol = (w >> 1) * 64;
  int rba[4], rbb[4];
#pragma unroll
  for (int i = 0; i < 4; ++i) {
    rba[i] = (mrow + 16 * i + (l & 15)) * 64;
    rbb[i] = (ncol + 16 * i + (l & 15)) * 64;
  }

  for (int k0 = 0; k0 < D_DIM; k0 += 64) {
    __syncthreads();
#pragma unroll
    for (int i = 0; i < 4; ++i) {
      glds16(ap[i] + k0,                As  + (w * 4 + i) * 512);
      glds16(bgp + k0 + i * 8 * D_DIM,  Bgs + (w * 4 + i) * 512);
      glds16(bup + k0 + i * 8 * D_DIM,  Bus + (w * 4 + i) * 512);
    }
    __syncthreads();
#pragma unroll
    for (int s = 0; s < 2; ++s) {
      const int pq = ((((s << 2) | (l >> 4)) ^ (l & 7)) << 3);
      short8 a[4], bg[4], bu[4];
#pragma unroll
      for (int i = 0; i < 4; ++i) a[i] = *(const short8*)(As + rba[i] + pq);
#pragma unroll
      for (int j = 0; j < 4; ++j) {
        bg[j] = *(const short8*)(Bgs + rbb[j] + pq);
        bu[j] = *(const short8*)(Bus + rbb[j] + pq);
      }
#pragma unroll
      for (int i = 0; i < 4; ++i)
#pragma unroll
        for (int j = 0; j < 4; ++j) {
          accg[i][j] = __builtin_amdgcn_mfma_f32_16x16x32_bf16(a[i], bg[j], accg[i][j], 0, 0, 0);
          accu[i][j] = __builtin_amdgcn_mfma_f32_16x16x32_bf16(a[i], bu[j], accu[i][j], 0, 0, 0);
        }
    }
  }

#pragma unroll
  for (int i = 0; i < 4; ++i) {
#pragma unroll
    for (int r = 0; r < 4; ++r) {
      int lrow = mrow + 16 * i + (l >> 4) * 4 + r;
      if (r0 + lrow < n_e) {
#pragma unroll
        for (int j = 0; j < 4; ++j) {
          float g = accg[i][j][r];
          float u = accu[i][j][r];
          float hv = (g / (1.f + __expf(-g))) * u;
          int col = c0 + ncol + 16 * j + (l & 15);
          h[(size_t)(hrow0 + lrow) * H_DIM + col] = f2bf(hv);
        }
      }
    }
  }
}

// ---------------- GEMM2: down-proj + weighted scatter-add ----------------
// grid: x = D col-tile (8), y = row-tile (32), z = expert (9)
__global__ __launch_bounds__(256, 3)
void gemm2_kernel(const ushort* __restrict__ h,
                  const ushort* __restrict__ Wdb, const ushort* __restrict__ sdb,
                  const int* __restrict__ list, const float* __restrict__ wlist,
                  const int* __restrict__ counts, const int* __restrict__ offs,
                  float* __restrict__ out) {
  const int e = blockIdx.z;
  const int n_e = (e == 8) ? T_TOK : counts[e];
  const int r0 = blockIdx.y * 128;
  if (r0 >= n_e) return;
  const int c0 = blockIdx.x * 128;
  const ushort* Wd = (e == 8) ? sdb : (Wdb + (size_t)e * D_DIM * H_DIM);
  const int hrow0 = offs[e] + r0;

  __shared__ __align__(16) ushort As[128 * 64];
  __shared__ __align__(16) ushort Bs[128 * 64];
  __shared__ int toks[128];
  __shared__ float wts[128];

  const int tid = threadIdx.x;
  const int l = tid & 63;
  const int w = tid >> 6;

  if (tid < 128) {
    int rr = r0 + tid;
    if (e == 8) {
      toks[tid] = (rr < T_TOK) ? rr : (T_TOK - 1);
      wts[tid] = 1.0f;
    } else {
      int idx = (rr < n_e) ? rr : (n_e - 1);
      toks[tid] = list[e * T_TOK + idx];
      wts[tid] = (rr < n_e) ? wlist[e * T_TOK + idx] : 0.f;
    }
  }

  const int lrow8 = l >> 3;
  const int csw = (((l & 7) ^ lrow8) << 3);
  const ushort* apb = h  + (size_t)(hrow0 + w * 32 + lrow8) * H_DIM + csw;
  const ushort* bpb = Wd + (size_t)(c0 + w * 32 + lrow8) * H_DIM + csw;

  floatx4 acc[4][4];
#pragma unroll
  for (int i = 0; i < 4; ++i)
#pragma unroll
    for (int j = 0; j < 4; ++j) acc[i][j] = (floatx4)(0.f);

  const int mrow = (w & 1) * 64;
  const int ncol = (w >> 1) * 64;
  int rba[4], rbb[4];
#pragma unroll
  for (int i = 0; i < 4; ++i) {
    rba[i] = (mrow + 16 * i + (l & 15)) * 64;
    rbb[i] = (ncol + 16 * i + (l & 15)) * 64;
  }

  for (int k0 = 0; k0 < H_DIM; k0 += 64) {
    __syncthreads();
#pragma unroll
    for (int i = 0; i < 4; ++i) {
      glds16(apb + k0 + i * 8 * H_DIM, As + (w * 4 + i) * 512);
      glds16(bpb + k0 + i * 8 * H_DIM, Bs + (w * 4 + i) * 512);
    }
    __syncthreads();
#pragma unroll
    for (int s = 0; s < 2; ++s) {
      const int pq = ((((s << 2) | (l >> 4)) ^ (l & 7)) << 3);
      short8 a[4], b[4];
#pragma unroll
      for (int i = 0; i < 4; ++i) a[i] = *(const short8*)(As + rba[i] + pq);
#pragma unroll
      for (int j = 0; j < 4; ++j) b[j] = *(const short8*)(Bs + rbb[j] + pq);
#pragma unroll
      for (int i = 0; i < 4; ++i)
#pragma unroll
        for (int j = 0; j < 4; ++j)
          acc[i][j] = __builtin_amdgcn_mfma_f32_16x16x32_bf16(a[i], b[j], acc[i][j], 0, 0, 0);
    }
  }

#pragma unroll
  for (int i = 0; i < 4; ++i) {
#pragma unroll
    for (int r = 0; r < 4; ++r) {
      int lrow = mrow + 16 * i + (l >> 4) * 4 + r;
      if (r0 + lrow < n_e) {
        int tok = toks[lrow];
        float wt = wts[lrow];
#pragma unroll
        for (int j = 0; j < 4; ++j) {
          int col = c0 + ncol + 16 * j + (l & 15);
          atomicAdd(&out[(size_t)tok * D_DIM + col], wt * acc[i][j][r]);
        }
      }
    }
  }
}

// ---------------- workspace layout ----------------
#define OFF_XB   0ull
#define OFF_WGB  (OFF_XB + 8388608ull)
#define OFF_WUB  (OFF_WGB + 33554432ull)
#define OFF_WDB  (OFF_WUB + 33554432ull)
#define OFF_SGB  (OFF_WDB + 33554432ull)
#define OFF_SUB  (OFF_SGB + 4194304ull)
#define OFF_SDB  (OFF_SUB + 4194304ull)
#define OFF_H    (OFF_SDB + 4194304ull)
#define OFF_CNT  (OFF_H + 50331648ull)
#define OFF_OFFS (OFF_CNT + 64ull)
#define OFF_LIST (OFF_OFFS + 64ull)
#define OFF_WLST (OFF_LIST + 131072ull)
#define OFF_TOPI (OFF_WLST + 131072ull)
#define OFF_TOPW (OFF_TOPI + 16384ull)

extern "C" void kernel_launch(void* const* d_in, const int* in_sizes, int n_in,
                              void* d_out, int out_size, void* d_ws, size_t ws_size,
                              hipStream_t stream) {
  const float* x  = (const float*)d_in[0];
  const float* wr = (const float*)d_in[1];
  const float* Wg = (const float*)d_in[2];
  const float* Wu = (const float*)d_in[3];
  const float* Wd = (const float*)d_in[4];
  const float* sg = (const float*)d_in[5];
  const float* su = (const float*)d_in[6];
  const float* sd = (const float*)d_in[7];
  float* out = (float*)d_out;
  char* ws = (char*)d_ws;

  ushort* xb  = (ushort*)(ws + OFF_XB);
  ushort* Wgb = (ushort*)(ws + OFF_WGB);
  ushort* Wub = (ushort*)(ws + OFF_WUB);
  ushort* Wdb = (ushort*)(ws + OFF_WDB);
  ushort* sgb = (ushort*)(ws + OFF_SGB);
  ushort* sub = (ushort*)(ws + OFF_SUB);
  ushort* sdb = (ushort*)(ws + OFF_SDB);
  ushort* hbuf = (ushort*)(ws + OFF_H);
  int* counts = (int*)(ws + OFF_CNT);
  int* offs   = (int*)(ws + OFF_OFFS);
  int* list   = (int*)(ws + OFF_LIST);
  float* wlist = (float*)(ws + OFF_WLST);
  int* topi   = (int*)(ws + OFF_TOPI);
  float2* topw = (float2*)(ws + OFF_TOPW);

  hipMemsetAsync(d_out, 0, (size_t)out_size * sizeof(float), stream);

  cvt_all_kernel<<<55296, 256, 0, stream>>>((const float4*)Wg, (ushort4*)Wgb,
                                            (const float4*)Wu, (ushort4*)Wub,
                                            (const float4*)Wd, (ushort4*)Wdb,
                                            (const float4*)sg, (ushort4*)sgb,
                                            (const float4*)su, (ushort4*)sub,
                                            (const float4*)sd, (ushort4*)sdb);

  router_kernel<<<1024, 256, 0, stream>>>(x, wr, xb, topi, topw);
  build_lists_kernel<<<8, 256, 0, stream>>>(topi, topw, counts, list, wlist);
  offsets_kernel<<<1, 64, 0, stream>>>(counts, offs);

  gemm1_kernel<<<dim3(16, 32, 9), 256, 0, stream>>>(xb, Wgb, Wub, sgb, sub,
                                                    list, counts, offs, hbuf);
  gemm2_kernel<<<dim3(8, 32, 9), 256, 0, stream>>>(hbuf, Wdb, sdb,
                                                   list, wlist, counts, offs, out);
}

// Round 4
// 475.821 us; speedup vs baseline: 1.2796x; 1.0113x over previous
//
#include <hip/hip_runtime.h>
#include <hip/hip_bf16.h>

#define T_TOK 4096
#define D_DIM 1024
#define H_DIM 2048

typedef __attribute__((ext_vector_type(8))) short short8;
typedef __attribute__((ext_vector_type(4))) float floatx4;

__device__ __forceinline__ unsigned short f2bf(float f) {
  unsigned int u = __builtin_bit_cast(unsigned int, f);
  return (unsigned short)((u + 0x7fffu + ((u >> 16) & 1u)) >> 16);
}

__device__ __forceinline__ float bf2f(unsigned short s) {
  unsigned int u = ((unsigned int)s) << 16;
  return __builtin_bit_cast(float, u);
}

__device__ __forceinline__ void glds16(const ushort* g, ushort* l) {
  __builtin_amdgcn_global_load_lds(
      (const __attribute__((address_space(1))) unsigned int*)g,
      (__attribute__((address_space(3))) unsigned int*)l, 16, 0, 0);
}

// ---------------- fp32 -> bf16: Wg, Wu, sg, su only (Wd/sd done in gemm1 prologue) ----------------
// flat float4 index space: Wg [0,4194304) Wu [..,8388608) sg [..,8912896) su [..,9437184)
__global__ void cvt_kernel(const float4* __restrict__ Wg, ushort4* __restrict__ Wgb,
                           const float4* __restrict__ Wu, ushort4* __restrict__ Wub,
                           const float4* __restrict__ sg, ushort4* __restrict__ sgb,
                           const float4* __restrict__ su, ushort4* __restrict__ sub) {
  int id = blockIdx.x * 256 + threadIdx.x;
  const float4* s; ushort4* d; int i;
  if (id < 4194304)      { s = Wg; d = Wgb; i = id; }
  else if (id < 8388608) { s = Wu; d = Wub; i = id - 4194304; }
  else if (id < 8912896) { s = sg; d = sgb; i = id - 8388608; }
  else                   { s = su; d = sub; i = id - 8912896; }
  float4 v = s[i];
  ushort4 o;
  o.x = f2bf(v.x); o.y = f2bf(v.y); o.z = f2bf(v.z); o.w = f2bf(v.w);
  d[i] = o;
}

// ---------------- router: logits, softmax, top-2 per token; fused x->bf16; NO atomics ----------------
__global__ void router_kernel(const float* __restrict__ x, const float* __restrict__ wr,
                              ushort* __restrict__ xb,
                              int* __restrict__ topi, float2* __restrict__ topw) {
  const int w = threadIdx.x >> 6;
  const int l = threadIdx.x & 63;
  const int t = blockIdx.x * 4 + w;  // one token per wave
  const float4* xr = (const float4*)(x + (size_t)t * D_DIM);
  ushort4* xo = (ushort4*)(xb + (size_t)t * D_DIM);
  float p[8];
#pragma unroll
  for (int e = 0; e < 8; ++e) p[e] = 0.f;
#pragma unroll
  for (int i = 0; i < 4; ++i) {
    float4 xv = xr[i * 64 + l];
    ushort4 o;
    o.x = f2bf(xv.x); o.y = f2bf(xv.y); o.z = f2bf(xv.z); o.w = f2bf(xv.w);
    xo[i * 64 + l] = o;
#pragma unroll
    for (int e = 0; e < 8; ++e) {
      float4 wv = ((const float4*)(wr + e * D_DIM))[i * 64 + l];
      p[e] += xv.x * wv.x + xv.y * wv.y + xv.z * wv.z + xv.w * wv.w;
    }
  }
#pragma unroll
  for (int off = 32; off > 0; off >>= 1) {
#pragma unroll
    for (int e = 0; e < 8; ++e) p[e] += __shfl_xor(p[e], off, 64);
  }
  if (l == 0) {
    float mx = p[0];
#pragma unroll
    for (int e = 1; e < 8; ++e) mx = fmaxf(mx, p[e]);
    float pr[8];
#pragma unroll
    for (int e = 0; e < 8; ++e) pr[e] = __expf(p[e] - mx);
    int i0 = 0;
#pragma unroll
    for (int e = 1; e < 8; ++e) if (pr[e] > pr[i0]) i0 = e;
    int i1 = (i0 == 0) ? 1 : 0;
#pragma unroll
    for (int e = 0; e < 8; ++e) if (e != i0 && pr[e] > pr[i1]) i1 = e;
    float w0 = pr[i0], w1 = pr[i1];
    float inv = 1.f / (w0 + w1);
    topi[t] = i0 | (i1 << 8);
    topw[t] = make_float2(w0 * inv, w1 * inv);
  }
}

// ---------------- deterministic list build + per-token position map ----------------
__global__ void build_lists_kernel(const int* __restrict__ topi,
                                   int* __restrict__ counts, int* __restrict__ list,
                                   int* __restrict__ pos) {
  const int e = blockIdx.x;
  const int tid = threadIdx.x;
  const int l = tid & 63;
  const int w = tid >> 6;
  __shared__ int wtot[4];
  int base = 0;
  for (int c = 0; c < T_TOK; c += 256) {
    int t = c + tid;
    int ti = topi[t];
    int e0 = ti & 255, e1 = ti >> 8;
    bool flag = (e0 == e) || (e1 == e);
    unsigned long long m = __ballot(flag);
    int lanepos = __popcll(m & ((1ull << l) - 1ull));
    if (l == 0) wtot[w] = __popcll(m);
    __syncthreads();
    int waveoff = 0;
#pragma unroll
    for (int i = 0; i < 4; ++i) waveoff += (i < w) ? wtot[i] : 0;
    int tot = wtot[0] + wtot[1] + wtot[2] + wtot[3];
    if (flag) {
      int p = base + waveoff + lanepos;
      list[e * T_TOK + p] = t;
      int slot = (e0 == e) ? 0 : 1;
      pos[t * 2 + slot] = p;
    }
    base += tot;
    __syncthreads();
  }
  if (tid == 0) counts[e] = base;
}

// ---------------- GEMM1: fused gate+up, SwiGLU epilogue -> h (bf16); Wd/sd cvt prologue ----------------
// BK=64, XOR bank swizzle. grid: x = H col-tile (16), y = row-tile (32), z = expert (9; 8 == shared)
__global__ __launch_bounds__(256, 2)
void gemm1_kernel(const ushort* __restrict__ xb,
                  const ushort* __restrict__ Wgb, const ushort* __restrict__ Wub,
                  const ushort* __restrict__ sgb, const ushort* __restrict__ sub,
                  const float4* __restrict__ Wd, ushort4* __restrict__ Wdb,
                  const float4* __restrict__ sd, ushort4* __restrict__ sdb,
                  const int* __restrict__ list, const int* __restrict__ counts,
                  ushort* __restrict__ h) {
  const int tid = threadIdx.x;
  // --- prologue: distributed fp32->bf16 of Wd (4,194,304 f4) and sd (524,288 f4) ---
  {
    int bid = blockIdx.x + 16 * blockIdx.y + 512 * blockIdx.z;  // 0..4607
#pragma unroll
    for (int it = 0; it < 4; ++it) {
      int idx = (bid * 4 + it) * 256 + tid;
      if (idx < 4194304) {
        float4 v = Wd[idx];
        ushort4 o;
        o.x = f2bf(v.x); o.y = f2bf(v.y); o.z = f2bf(v.z); o.w = f2bf(v.w);
        Wdb[idx] = o;
      }
    }
    if (bid < 2048) {
      int idx = bid * 256 + tid;
      float4 v = sd[idx];
      ushort4 o;
      o.x = f2bf(v.x); o.y = f2bf(v.y); o.z = f2bf(v.z); o.w = f2bf(v.w);
      sdb[idx] = o;
    }
  }

  const int e = blockIdx.z;
  int n_e, hbase;
  {
    int acc = 0, ce = 0;
    for (int q = 0; q < 8; ++q) {
      int c = counts[q];
      if (q < e) acc += c;
      if (q == e) ce = c;
    }
    n_e = (e == 8) ? T_TOK : ce;
    hbase = (e == 8) ? 8192 : acc;
  }
  const int r0 = blockIdx.y * 128;
  if (r0 >= n_e) return;
  const int c0 = blockIdx.x * 128;
  const ushort* Wg = (e == 8) ? sgb : (Wgb + (size_t)e * H_DIM * D_DIM);
  const ushort* Wu = (e == 8) ? sub : (Wub + (size_t)e * H_DIM * D_DIM);
  const int hrow0 = hbase + r0;

  __shared__ __align__(16) ushort As[128 * 64];
  __shared__ __align__(16) ushort Bgs[128 * 64];
  __shared__ __align__(16) ushort Bus[128 * 64];
  __shared__ int toks[128];

  const int l = tid & 63;
  const int w = tid >> 6;

  if (tid < 128) {
    int rr = r0 + tid;
    toks[tid] = (e == 8) ? ((rr < T_TOK) ? rr : (T_TOK - 1))
                         : list[e * T_TOK + ((rr < n_e) ? rr : (n_e - 1))];
  }
  __syncthreads();

  const int lrow8 = l >> 3;
  const int csw = (((l & 7) ^ lrow8) << 3);  // XOR-swizzled k-chunk (element offset)
  const ushort* ap[4];
#pragma unroll
  for (int i = 0; i < 4; ++i) {
    int ri = (w * 4 + i) * 8 + lrow8;
    ap[i] = xb + (size_t)toks[ri] * D_DIM + csw;
  }
  const ushort* bgp = Wg + (size_t)(c0 + w * 32 + lrow8) * D_DIM + csw;
  const ushort* bup = Wu + (size_t)(c0 + w * 32 + lrow8) * D_DIM + csw;

  floatx4 accg[4][4], accu[4][4];
#pragma unroll
  for (int i = 0; i < 4; ++i)
#pragma unroll
    for (int j = 0; j < 4; ++j) {
      accg[i][j] = (floatx4)(0.f);
      accu[i][j] = (floatx4)(0.f);
    }

  const int mrow = (w & 1) * 64;
  const int ncol = (w >> 1) * 64;
  int rba[4], rbb[4];
#pragma unroll
  for (int i = 0; i < 4; ++i) {
    rba[i] = (mrow + 16 * i + (l & 15)) * 64;
    rbb[i] = (ncol + 16 * i + (l & 15)) * 64;
  }

  for (int k0 = 0; k0 < D_DIM; k0 += 64) {
    __syncthreads();
#pragma unroll
    for (int i = 0; i < 4; ++i) {
      glds16(ap[i] + k0,                As  + (w * 4 + i) * 512);
      glds16(bgp + k0 + i * 8 * D_DIM,  Bgs + (w * 4 + i) * 512);
      glds16(bup + k0 + i * 8 * D_DIM,  Bus + (w * 4 + i) * 512);
    }
    __syncthreads();
#pragma unroll
    for (int s = 0; s < 2; ++s) {
      const int pq = ((((s << 2) | (l >> 4)) ^ (l & 7)) << 3);
      short8 a[4], bg[4], bu[4];
#pragma unroll
      for (int i = 0; i < 4; ++i) a[i] = *(const short8*)(As + rba[i] + pq);
#pragma unroll
      for (int j = 0; j < 4; ++j) {
        bg[j] = *(const short8*)(Bgs + rbb[j] + pq);
        bu[j] = *(const short8*)(Bus + rbb[j] + pq);
      }
#pragma unroll
      for (int i = 0; i < 4; ++i)
#pragma unroll
        for (int j = 0; j < 4; ++j) {
          accg[i][j] = __builtin_amdgcn_mfma_f32_16x16x32_bf16(a[i], bg[j], accg[i][j], 0, 0, 0);
          accu[i][j] = __builtin_amdgcn_mfma_f32_16x16x32_bf16(a[i], bu[j], accu[i][j], 0, 0, 0);
        }
    }
  }

#pragma unroll
  for (int i = 0; i < 4; ++i) {
#pragma unroll
    for (int r = 0; r < 4; ++r) {
      int lrow = mrow + 16 * i + (l >> 4) * 4 + r;
      if (r0 + lrow < n_e) {
#pragma unroll
        for (int j = 0; j < 4; ++j) {
          float g = accg[i][j][r];
          float u = accu[i][j][r];
          float hv = (g / (1.f + __expf(-g))) * u;
          int col = c0 + ncol + 16 * j + (l & 15);
          h[(size_t)(hrow0 + lrow) * H_DIM + col] = f2bf(hv);
        }
      }
    }
  }
}

// ---------------- GEMM2: down-proj -> eo rows (bf16), non-atomic ----------------
// grid: x = D col-tile (8), y = row-tile (32), z = expert (9)
__global__ __launch_bounds__(256, 3)
void gemm2_kernel(const ushort* __restrict__ h,
                  const ushort* __restrict__ Wdb, const ushort* __restrict__ sdb,
                  const int* __restrict__ counts,
                  ushort* __restrict__ eo) {
  const int e = blockIdx.z;
  int n_e, hbase;
  {
    int acc = 0, ce = 0;
    for (int q = 0; q < 8; ++q) {
      int c = counts[q];
      if (q < e) acc += c;
      if (q == e) ce = c;
    }
    n_e = (e == 8) ? T_TOK : ce;
    hbase = (e == 8) ? 8192 : acc;
  }
  const int r0 = blockIdx.y * 128;
  if (r0 >= n_e) return;
  const int c0 = blockIdx.x * 128;
  const ushort* Wd = (e == 8) ? sdb : (Wdb + (size_t)e * D_DIM * H_DIM);
  const int hrow0 = hbase + r0;

  __shared__ __align__(16) ushort As[128 * 64];
  __shared__ __align__(16) ushort Bs[128 * 64];

  const int tid = threadIdx.x;
  const int l = tid & 63;
  const int w = tid >> 6;

  const int lrow8 = l >> 3;
  const int csw = (((l & 7) ^ lrow8) << 3);
  const ushort* apb = h  + (size_t)(hrow0 + w * 32 + lrow8) * H_DIM + csw;
  const ushort* bpb = Wd + (size_t)(c0 + w * 32 + lrow8) * H_DIM + csw;

  floatx4 acc[4][4];
#pragma unroll
  for (int i = 0; i < 4; ++i)
#pragma unroll
    for (int j = 0; j < 4; ++j) acc[i][j] = (floatx4)(0.f);

  const int mrow = (w & 1) * 64;
  const int ncol = (w >> 1) * 64;
  int rba[4], rbb[4];
#pragma unroll
  for (int i = 0; i < 4; ++i) {
    rba[i] = (mrow + 16 * i + (l & 15)) * 64;
    rbb[i] = (ncol + 16 * i + (l & 15)) * 64;
  }

  for (int k0 = 0; k0 < H_DIM; k0 += 64) {
    __syncthreads();
#pragma unroll
    for (int i = 0; i < 4; ++i) {
      glds16(apb + k0 + i * 8 * H_DIM, As + (w * 4 + i) * 512);
      glds16(bpb + k0 + i * 8 * H_DIM, Bs + (w * 4 + i) * 512);
    }
    __syncthreads();
#pragma unroll
    for (int s = 0; s < 2; ++s) {
      const int pq = ((((s << 2) | (l >> 4)) ^ (l & 7)) << 3);
      short8 a[4], b[4];
#pragma unroll
      for (int i = 0; i < 4; ++i) a[i] = *(const short8*)(As + rba[i] + pq);
#pragma unroll
      for (int j = 0; j < 4; ++j) b[j] = *(const short8*)(Bs + rbb[j] + pq);
#pragma unroll
      for (int i = 0; i < 4; ++i)
#pragma unroll
        for (int j = 0; j < 4; ++j)
          acc[i][j] = __builtin_amdgcn_mfma_f32_16x16x32_bf16(a[i], b[j], acc[i][j], 0, 0, 0);
    }
  }

  // epilogue: plain bf16 stores into eo rows (combine applies weights later)
#pragma unroll
  for (int i = 0; i < 4; ++i) {
#pragma unroll
    for (int r = 0; r < 4; ++r) {
      int lrow = mrow + 16 * i + (l >> 4) * 4 + r;
      if (r0 + lrow < n_e) {
#pragma unroll
        for (int j = 0; j < 4; ++j) {
          int col = c0 + ncol + 16 * j + (l & 15);
          eo[(size_t)(hrow0 + lrow) * D_DIM + col] = f2bf(acc[i][j][r]);
        }
      }
    }
  }
}

// ---------------- combine: out[t] = w0*eo[row(e0)] + w1*eo[row(e1)] + eo[8192+t] ----------------
__global__ void combine_kernel(const ushort* __restrict__ eo, const int* __restrict__ topi,
                               const float2* __restrict__ topw, const int* __restrict__ pos,
                               const int* __restrict__ counts, float* __restrict__ out) {
  const int t = blockIdx.x;
  const int c4 = threadIdx.x;  // 4 cols each
  int ti = topi[t];
  int e0 = ti & 255, e1 = ti >> 8;
  int off0 = 0, off1 = 0;
#pragma unroll
  for (int q = 0; q < 8; ++q) {
    int c = counts[q];
    off0 += (q < e0) ? c : 0;
    off1 += (q < e1) ? c : 0;
  }
  float2 wv = topw[t];
  int2 p = ((const int2*)pos)[t];
  const ushort4* ra = (const ushort4*)(eo + (size_t)(off0 + p.x) * D_DIM);
  const ushort4* rb = (const ushort4*)(eo + (size_t)(off1 + p.y) * D_DIM);
  const ushort4* rs = (const ushort4*)(eo + (size_t)(8192 + t) * D_DIM);
  ushort4 a = ra[c4], b = rb[c4], s = rs[c4];
  float4 o;
  o.x = wv.x * bf2f(a.x) + wv.y * bf2f(b.x) + bf2f(s.x);
  o.y = wv.x * bf2f(a.y) + wv.y * bf2f(b.y) + bf2f(s.y);
  o.z = wv.x * bf2f(a.z) + wv.y * bf2f(b.z) + bf2f(s.z);
  o.w = wv.x * bf2f(a.w) + wv.y * bf2f(b.w) + bf2f(s.w);
  ((float4*)(out + (size_t)t * D_DIM))[c4] = o;
}

// ---------------- workspace layout ----------------
#define OFF_XB   0ull
#define OFF_WGB  (OFF_XB + 8388608ull)
#define OFF_WUB  (OFF_WGB + 33554432ull)
#define OFF_WDB  (OFF_WUB + 33554432ull)
#define OFF_SGB  (OFF_WDB + 33554432ull)
#define OFF_SUB  (OFF_SGB + 4194304ull)
#define OFF_SDB  (OFF_SUB + 4194304ull)
#define OFF_H    (OFF_SDB + 4194304ull)
#define OFF_EO   OFF_WGB  /* eo aliases Wgb: Wgb dead after gemm1, eo written by gemm2 */
#define OFF_CNT  (OFF_H + 50331648ull)
#define OFF_LIST (OFF_CNT + 64ull)
#define OFF_POS  (OFF_LIST + 131072ull)
#define OFF_TOPI (OFF_POS + 32768ull)
#define OFF_TOPW (OFF_TOPI + 16384ull)

extern "C" void kernel_launch(void* const* d_in, const int* in_sizes, int n_in,
                              void* d_out, int out_size, void* d_ws, size_t ws_size,
                              hipStream_t stream) {
  const float* x  = (const float*)d_in[0];
  const float* wr = (const float*)d_in[1];
  const float* Wg = (const float*)d_in[2];
  const float* Wu = (const float*)d_in[3];
  const float* Wd = (const float*)d_in[4];
  const float* sg = (const float*)d_in[5];
  const float* su = (const float*)d_in[6];
  const float* sd = (const float*)d_in[7];
  float* out = (float*)d_out;
  char* ws = (char*)d_ws;

  ushort* xb  = (ushort*)(ws + OFF_XB);
  ushort* Wgb = (ushort*)(ws + OFF_WGB);
  ushort* Wub = (ushort*)(ws + OFF_WUB);
  ushort* Wdb = (ushort*)(ws + OFF_WDB);
  ushort* sgb = (ushort*)(ws + OFF_SGB);
  ushort* sub = (ushort*)(ws + OFF_SUB);
  ushort* sdb = (ushort*)(ws + OFF_SDB);
  ushort* hbuf = (ushort*)(ws + OFF_H);
  ushort* eo   = (ushort*)(ws + OFF_EO);
  int* counts = (int*)(ws + OFF_CNT);
  int* list   = (int*)(ws + OFF_LIST);
  int* pos    = (int*)(ws + OFF_POS);
  int* topi   = (int*)(ws + OFF_TOPI);
  float2* topw = (float2*)(ws + OFF_TOPW);

  cvt_kernel<<<36864, 256, 0, stream>>>((const float4*)Wg, (ushort4*)Wgb,
                                        (const float4*)Wu, (ushort4*)Wub,
                                        (const float4*)sg, (ushort4*)sgb,
                                        (const float4*)su, (ushort4*)sub);

  router_kernel<<<1024, 256, 0, stream>>>(x, wr, xb, topi, topw);
  build_lists_kernel<<<8, 256, 0, stream>>>(topi, counts, list, pos);

  gemm1_kernel<<<dim3(16, 32, 9), 256, 0, stream>>>(xb, Wgb, Wub, sgb, sub,
                                                    (const float4*)Wd, (ushort4*)Wdb,
                                                    (const float4*)sd, (ushort4*)sdb,
                                                    list, counts, hbuf);
  gemm2_kernel<<<dim3(8, 32, 9), 256, 0, stream>>>(hbuf, Wdb, sdb, counts, eo);
  combine_kernel<<<4096, 256, 0, stream>>>(eo, topi, topw, pos, counts, out);
}

// Round 5
// 447.245 us; speedup vs baseline: 1.3613x; 1.0639x over previous
//
#include <hip/hip_runtime.h>
#include <hip/hip_bf16.h>

#define T_TOK 4096
#define D_DIM 1024
#define H_DIM 2048

typedef __attribute__((ext_vector_type(8))) short short8;
typedef __attribute__((ext_vector_type(4))) float floatx4;

__device__ __forceinline__ unsigned short f2bf(float f) {
  unsigned int u = __builtin_bit_cast(unsigned int, f);
  return (unsigned short)((u + 0x7fffu + ((u >> 16) & 1u)) >> 16);
}

__device__ __forceinline__ float bf2f(unsigned short s) {
  unsigned int u = ((unsigned int)s) << 16;
  return __builtin_bit_cast(float, u);
}

__device__ __forceinline__ void glds16(const ushort* g, ushort* l) {
  __builtin_amdgcn_global_load_lds(
      (const __attribute__((address_space(1))) unsigned int*)g,
      (__attribute__((address_space(3))) unsigned int*)l, 16, 0, 0);
}

// ---------------- prep: fp32->bf16 of all 6 weight tensors + router, one launch ----------------
// blocks [0, 55296): cvt, flat float4 space 14,155,776
//   Wg [0, 4194304) Wu [.., 8388608) Wd [.., 12582912) sg [.., 13107200) su [.., 13631488) sd [.., 14155776)
// blocks [55296, 56320): router (4 tokens per block, 1 per wave)
__global__ void prep_kernel(const float4* __restrict__ Wg, ushort4* __restrict__ Wgb,
                            const float4* __restrict__ Wu, ushort4* __restrict__ Wub,
                            const float4* __restrict__ Wd, ushort4* __restrict__ Wdb,
                            const float4* __restrict__ sg, ushort4* __restrict__ sgb,
                            const float4* __restrict__ su, ushort4* __restrict__ sub,
                            const float4* __restrict__ sd, ushort4* __restrict__ sdb,
                            const float* __restrict__ x, const float* __restrict__ wr,
                            ushort* __restrict__ xb,
                            int* __restrict__ topi, float2* __restrict__ topw) {
  if (blockIdx.x < 55296) {
    int id = blockIdx.x * 256 + threadIdx.x;
    const float4* s; ushort4* d; int i;
    if (id < 4194304)       { s = Wg; d = Wgb; i = id; }
    else if (id < 8388608)  { s = Wu; d = Wub; i = id - 4194304; }
    else if (id < 12582912) { s = Wd; d = Wdb; i = id - 8388608; }
    else if (id < 13107200) { s = sg; d = sgb; i = id - 12582912; }
    else if (id < 13631488) { s = su; d = sub; i = id - 13107200; }
    else                    { s = sd; d = sdb; i = id - 13631488; }
    float4 v = s[i];
    ushort4 o;
    o.x = f2bf(v.x); o.y = f2bf(v.y); o.z = f2bf(v.z); o.w = f2bf(v.w);
    d[i] = o;
    return;
  }
  // ---- router ----
  const int w = threadIdx.x >> 6;
  const int l = threadIdx.x & 63;
  const int t = (blockIdx.x - 55296) * 4 + w;  // one token per wave
  const float4* xr = (const float4*)(x + (size_t)t * D_DIM);
  ushort4* xo = (ushort4*)(xb + (size_t)t * D_DIM);
  float p[8];
#pragma unroll
  for (int e = 0; e < 8; ++e) p[e] = 0.f;
#pragma unroll
  for (int i = 0; i < 4; ++i) {
    float4 xv = xr[i * 64 + l];
    ushort4 o;
    o.x = f2bf(xv.x); o.y = f2bf(xv.y); o.z = f2bf(xv.z); o.w = f2bf(xv.w);
    xo[i * 64 + l] = o;
#pragma unroll
    for (int e = 0; e < 8; ++e) {
      float4 wv = ((const float4*)(wr + e * D_DIM))[i * 64 + l];
      p[e] += xv.x * wv.x + xv.y * wv.y + xv.z * wv.z + xv.w * wv.w;
    }
  }
#pragma unroll
  for (int off = 32; off > 0; off >>= 1) {
#pragma unroll
    for (int e = 0; e < 8; ++e) p[e] += __shfl_xor(p[e], off, 64);
  }
  if (l == 0) {
    float mx = p[0];
#pragma unroll
    for (int e = 1; e < 8; ++e) mx = fmaxf(mx, p[e]);
    float pr[8];
#pragma unroll
    for (int e = 0; e < 8; ++e) pr[e] = __expf(p[e] - mx);
    int i0 = 0;
#pragma unroll
    for (int e = 1; e < 8; ++e) if (pr[e] > pr[i0]) i0 = e;
    int i1 = (i0 == 0) ? 1 : 0;
#pragma unroll
    for (int e = 0; e < 8; ++e) if (e != i0 && pr[e] > pr[i1]) i1 = e;
    float w0 = pr[i0], w1 = pr[i1];
    float inv = 1.f / (w0 + w1);
    topi[t] = i0 | (i1 << 8);
    topw[t] = make_float2(w0 * inv, w1 * inv);
  }
}

// ---------------- deterministic list build + per-token position map ----------------
__global__ void build_lists_kernel(const int* __restrict__ topi,
                                   int* __restrict__ counts, int* __restrict__ list,
                                   int* __restrict__ pos) {
  const int e = blockIdx.x;
  const int tid = threadIdx.x;
  const int l = tid & 63;
  const int w = tid >> 6;
  __shared__ int wtot[4];
  int base = 0;
  for (int c = 0; c < T_TOK; c += 256) {
    int t = c + tid;
    int ti = topi[t];
    int e0 = ti & 255, e1 = ti >> 8;
    bool flag = (e0 == e) || (e1 == e);
    unsigned long long m = __ballot(flag);
    int lanepos = __popcll(m & ((1ull << l) - 1ull));
    if (l == 0) wtot[w] = __popcll(m);
    __syncthreads();
    int waveoff = 0;
#pragma unroll
    for (int i = 0; i < 4; ++i) waveoff += (i < w) ? wtot[i] : 0;
    int tot = wtot[0] + wtot[1] + wtot[2] + wtot[3];
    if (flag) {
      int p = base + waveoff + lanepos;
      list[e * T_TOK + p] = t;
      int slot = (e0 == e) ? 0 : 1;
      pos[t * 2 + slot] = p;
    }
    base += tot;
    __syncthreads();
  }
  if (tid == 0) counts[e] = base;
}

// ---------------- GEMM1: fused gate+up, SwiGLU epilogue -> h (bf16) ----------------
// BK=64, XOR bank swizzle. grid: x = H col-tile (16), y = row-tile (32), z = expert (9; 8 == shared)
__global__ __launch_bounds__(256, 2)
void gemm1_kernel(const ushort* __restrict__ xb,
                  const ushort* __restrict__ Wgb, const ushort* __restrict__ Wub,
                  const ushort* __restrict__ sgb, const ushort* __restrict__ sub,
                  const int* __restrict__ list, const int* __restrict__ counts,
                  ushort* __restrict__ h) {
  const int e = blockIdx.z;
  int n_e, hbase;
  {
    int acc = 0, ce = 0;
    for (int q = 0; q < 8; ++q) {
      int c = counts[q];
      if (q < e) acc += c;
      if (q == e) ce = c;
    }
    n_e = (e == 8) ? T_TOK : ce;
    hbase = (e == 8) ? 8192 : acc;
  }
  const int r0 = blockIdx.y * 128;
  if (r0 >= n_e) return;
  const int c0 = blockIdx.x * 128;
  const ushort* Wg = (e == 8) ? sgb : (Wgb + (size_t)e * H_DIM * D_DIM);
  const ushort* Wu = (e == 8) ? sub : (Wub + (size_t)e * H_DIM * D_DIM);
  const int hrow0 = hbase + r0;

  __shared__ __align__(16) ushort As[128 * 64];
  __shared__ __align__(16) ushort Bgs[128 * 64];
  __shared__ __align__(16) ushort Bus[128 * 64];
  __shared__ int toks[128];

  const int tid = threadIdx.x;
  const int l = tid & 63;
  const int w = tid >> 6;

  if (tid < 128) {
    int rr = r0 + tid;
    toks[tid] = (e == 8) ? ((rr < T_TOK) ? rr : (T_TOK - 1))
                         : list[e * T_TOK + ((rr < n_e) ? rr : (n_e - 1))];
  }
  __syncthreads();

  const int lrow8 = l >> 3;
  const int csw = (((l & 7) ^ lrow8) << 3);  // XOR-swizzled k-chunk (element offset)
  const ushort* ap[4];
#pragma unroll
  for (int i = 0; i < 4; ++i) {
    int ri = (w * 4 + i) * 8 + lrow8;
    ap[i] = xb + (size_t)toks[ri] * D_DIM + csw;
  }
  const ushort* bgp = Wg + (size_t)(c0 + w * 32 + lrow8) * D_DIM + csw;
  const ushort* bup = Wu + (size_t)(c0 + w * 32 + lrow8) * D_DIM + csw;

  floatx4 accg[4][4], accu[4][4];
#pragma unroll
  for (int i = 0; i < 4; ++i)
#pragma unroll
    for (int j = 0; j < 4; ++j) {
      accg[i][j] = (floatx4)(0.f);
      accu[i][j] = (floatx4)(0.f);
    }

  const int mrow = (w & 1) * 64;
  const int ncol = (w >> 1) * 64;
  int rba[4], rbb[4];
#pragma unroll
  for (int i = 0; i < 4; ++i) {
    rba[i] = (mrow + 16 * i + (l & 15)) * 64;
    rbb[i] = (ncol + 16 * i + (l & 15)) * 64;
  }

  for (int k0 = 0; k0 < D_DIM; k0 += 64) {
    __syncthreads();
#pragma unroll
    for (int i = 0; i < 4; ++i) {
      glds16(ap[i] + k0,                As  + (w * 4 + i) * 512);
      glds16(bgp + k0 + i * 8 * D_DIM,  Bgs + (w * 4 + i) * 512);
      glds16(bup + k0 + i * 8 * D_DIM,  Bus + (w * 4 + i) * 512);
    }
    __syncthreads();
#pragma unroll
    for (int s = 0; s < 2; ++s) {
      const int pq = ((((s << 2) | (l >> 4)) ^ (l & 7)) << 3);
      short8 a[4], bg[4], bu[4];
#pragma unroll
      for (int i = 0; i < 4; ++i) a[i] = *(const short8*)(As + rba[i] + pq);
#pragma unroll
      for (int j = 0; j < 4; ++j) {
        bg[j] = *(const short8*)(Bgs + rbb[j] + pq);
        bu[j] = *(const short8*)(Bus + rbb[j] + pq);
      }
#pragma unroll
      for (int i = 0; i < 4; ++i)
#pragma unroll
        for (int j = 0; j < 4; ++j) {
          accg[i][j] = __builtin_amdgcn_mfma_f32_16x16x32_bf16(a[i], bg[j], accg[i][j], 0, 0, 0);
          accu[i][j] = __builtin_amdgcn_mfma_f32_16x16x32_bf16(a[i], bu[j], accu[i][j], 0, 0, 0);
        }
    }
  }

#pragma unroll
  for (int i = 0; i < 4; ++i) {
#pragma unroll
    for (int r = 0; r < 4; ++r) {
      int lrow = mrow + 16 * i + (l >> 4) * 4 + r;
      if (r0 + lrow < n_e) {
#pragma unroll
        for (int j = 0; j < 4; ++j) {
          float g = accg[i][j][r];
          float u = accu[i][j][r];
          float hv = (g / (1.f + __expf(-g))) * u;
          int col = c0 + ncol + 16 * j + (l & 15);
          h[(size_t)(hrow0 + lrow) * H_DIM + col] = f2bf(hv);
        }
      }
    }
  }
}

// ---------------- GEMM2: down-proj -> eo rows (bf16), 128x256 tile ----------------
// grid: x = D col-tile (4, 256 wide), y = row-tile (32), z = expert (9)
__global__ __launch_bounds__(256, 2)
void gemm2_kernel(const ushort* __restrict__ h,
                  const ushort* __restrict__ Wdb, const ushort* __restrict__ sdb,
                  const int* __restrict__ counts,
                  ushort* __restrict__ eo) {
  const int e = blockIdx.z;
  int n_e, hbase;
  {
    int acc = 0, ce = 0;
    for (int q = 0; q < 8; ++q) {
      int c = counts[q];
      if (q < e) acc += c;
      if (q == e) ce = c;
    }
    n_e = (e == 8) ? T_TOK : ce;
    hbase = (e == 8) ? 8192 : acc;
  }
  const int r0 = blockIdx.y * 128;
  if (r0 >= n_e) return;
  const int c0 = blockIdx.x * 256;
  const ushort* Wd = (e == 8) ? sdb : (Wdb + (size_t)e * D_DIM * H_DIM);
  const int hrow0 = hbase + r0;

  __shared__ __align__(16) ushort As[128 * 64];
  __shared__ __align__(16) ushort Bs[256 * 64];

  const int tid = threadIdx.x;
  const int l = tid & 63;
  const int w = tid >> 6;

  const int lrow8 = l >> 3;
  const int csw = (((l & 7) ^ lrow8) << 3);
  const ushort* apb = h  + (size_t)(hrow0 + w * 32 + lrow8) * H_DIM + csw;
  const ushort* bpb = Wd + (size_t)(c0 + w * 64 + lrow8) * H_DIM + csw;

  floatx4 acc[4][8];
#pragma unroll
  for (int i = 0; i < 4; ++i)
#pragma unroll
    for (int j = 0; j < 8; ++j) acc[i][j] = (floatx4)(0.f);

  const int mrow = (w & 1) * 64;
  const int ncol = (w >> 1) * 128;
  int rba[4], rbb[8];
#pragma unroll
  for (int i = 0; i < 4; ++i) rba[i] = (mrow + 16 * i + (l & 15)) * 64;
#pragma unroll
  for (int j = 0; j < 8; ++j) rbb[j] = (ncol + 16 * j + (l & 15)) * 64;

  for (int k0 = 0; k0 < H_DIM; k0 += 64) {
    __syncthreads();
#pragma unroll
    for (int i = 0; i < 4; ++i)
      glds16(apb + k0 + i * 8 * H_DIM, As + (w * 4 + i) * 512);
#pragma unroll
    for (int i = 0; i < 8; ++i)
      glds16(bpb + k0 + i * 8 * H_DIM, Bs + (w * 8 + i) * 512);
    __syncthreads();
#pragma unroll
    for (int s = 0; s < 2; ++s) {
      const int pq = ((((s << 2) | (l >> 4)) ^ (l & 7)) << 3);
      short8 a[4], b[8];
#pragma unroll
      for (int i = 0; i < 4; ++i) a[i] = *(const short8*)(As + rba[i] + pq);
#pragma unroll
      for (int j = 0; j < 8; ++j) b[j] = *(const short8*)(Bs + rbb[j] + pq);
#pragma unroll
      for (int i = 0; i < 4; ++i)
#pragma unroll
        for (int j = 0; j < 8; ++j)
          acc[i][j] = __builtin_amdgcn_mfma_f32_16x16x32_bf16(a[i], b[j], acc[i][j], 0, 0, 0);
    }
  }

#pragma unroll
  for (int i = 0; i < 4; ++i) {
#pragma unroll
    for (int r = 0; r < 4; ++r) {
      int lrow = mrow + 16 * i + (l >> 4) * 4 + r;
      if (r0 + lrow < n_e) {
#pragma unroll
        for (int j = 0; j < 8; ++j) {
          int col = c0 + ncol + 16 * j + (l & 15);
          eo[(size_t)(hrow0 + lrow) * D_DIM + col] = f2bf(acc[i][j][r]);
        }
      }
    }
  }
}

// ---------------- combine: out[t] = w0*eo[row(e0)] + w1*eo[row(e1)] + eo[8192+t] ----------------
__global__ void combine_kernel(const ushort* __restrict__ eo, const int* __restrict__ topi,
                               const float2* __restrict__ topw, const int* __restrict__ pos,
                               const int* __restrict__ counts, float* __restrict__ out) {
  const int t = blockIdx.x;
  const int c4 = threadIdx.x;  // 4 cols each
  int ti = topi[t];
  int e0 = ti & 255, e1 = ti >> 8;
  int off0 = 0, off1 = 0;
#pragma unroll
  for (int q = 0; q < 8; ++q) {
    int c = counts[q];
    off0 += (q < e0) ? c : 0;
    off1 += (q < e1) ? c : 0;
  }
  float2 wv = topw[t];
  int2 p = ((const int2*)pos)[t];
  const ushort4* ra = (const ushort4*)(eo + (size_t)(off0 + p.x) * D_DIM);
  const ushort4* rb = (const ushort4*)(eo + (size_t)(off1 + p.y) * D_DIM);
  const ushort4* rs = (const ushort4*)(eo + (size_t)(8192 + t) * D_DIM);
  ushort4 a = ra[c4], b = rb[c4], s = rs[c4];
  float4 o;
  o.x = wv.x * bf2f(a.x) + wv.y * bf2f(b.x) + bf2f(s.x);
  o.y = wv.x * bf2f(a.y) + wv.y * bf2f(b.y) + bf2f(s.y);
  o.z = wv.x * bf2f(a.z) + wv.y * bf2f(b.z) + bf2f(s.z);
  o.w = wv.x * bf2f(a.w) + wv.y * bf2f(b.w) + bf2f(s.w);
  ((float4*)(out + (size_t)t * D_DIM))[c4] = o;
}

// ---------------- workspace layout ----------------
#define OFF_XB   0ull
#define OFF_WGB  (OFF_XB + 8388608ull)
#define OFF_WUB  (OFF_WGB + 33554432ull)
#define OFF_WDB  (OFF_WUB + 33554432ull)
#define OFF_SGB  (OFF_WDB + 33554432ull)
#define OFF_SUB  (OFF_SGB + 4194304ull)
#define OFF_SDB  (OFF_SUB + 4194304ull)
#define OFF_H    (OFF_SDB + 4194304ull)
#define OFF_EO   OFF_WGB  /* eo aliases Wgb: Wgb dead after gemm1, eo written by gemm2 */
#define OFF_CNT  (OFF_H + 50331648ull)
#define OFF_LIST (OFF_CNT + 64ull)
#define OFF_POS  (OFF_LIST + 131072ull)
#define OFF_TOPI (OFF_POS + 32768ull)
#define OFF_TOPW (OFF_TOPI + 16384ull)

extern "C" void kernel_launch(void* const* d_in, const int* in_sizes, int n_in,
                              void* d_out, int out_size, void* d_ws, size_t ws_size,
                              hipStream_t stream) {
  const float* x  = (const float*)d_in[0];
  const float* wr = (const float*)d_in[1];
  const float* Wg = (const float*)d_in[2];
  const float* Wu = (const float*)d_in[3];
  const float* Wd = (const float*)d_in[4];
  const float* sg = (const float*)d_in[5];
  const float* su = (const float*)d_in[6];
  const float* sd = (const float*)d_in[7];
  float* out = (float*)d_out;
  char* ws = (char*)d_ws;

  ushort* xb  = (ushort*)(ws + OFF_XB);
  ushort* Wgb = (ushort*)(ws + OFF_WGB);
  ushort* Wub = (ushort*)(ws + OFF_WUB);
  ushort* Wdb = (ushort*)(ws + OFF_WDB);
  ushort* sgb = (ushort*)(ws + OFF_SGB);
  ushort* sub = (ushort*)(ws + OFF_SUB);
  ushort* sdb = (ushort*)(ws + OFF_SDB);
  ushort* hbuf = (ushort*)(ws + OFF_H);
  ushort* eo   = (ushort*)(ws + OFF_EO);
  int* counts = (int*)(ws + OFF_CNT);
  int* list   = (int*)(ws + OFF_LIST);
  int* pos    = (int*)(ws + OFF_POS);
  int* topi   = (int*)(ws + OFF_TOPI);
  float2* topw = (float2*)(ws + OFF_TOPW);

  prep_kernel<<<56320, 256, 0, stream>>>((const float4*)Wg, (ushort4*)Wgb,
                                         (const float4*)Wu, (ushort4*)Wub,
                                         (const float4*)Wd, (ushort4*)Wdb,
                                         (const float4*)sg, (ushort4*)sgb,
                                         (const float4*)su, (ushort4*)sub,
                                         (const float4*)sd, (ushort4*)sdb,
                                         x, wr, xb, topi, topw);
  build_lists_kernel<<<8, 256, 0, stream>>>(topi, counts, list, pos);

  gemm1_kernel<<<dim3(16, 32, 9), 256, 0, stream>>>(xb, Wgb, Wub, sgb, sub,
                                                    list, counts, hbuf);
  gemm2_kernel<<<dim3(4, 32, 9), 256, 0, stream>>>(hbuf, Wdb, sdb, counts, eo);
  combine_kernel<<<4096, 256, 0, stream>>>(eo, topi, topw, pos, counts, out);
}